// Round 16
// baseline (161.579 us; speedup 1.0000x reference)
//
#include <hip/hip_runtime.h>
#include <hip/hip_bf16.h>

#define H     256
#define BM    128
#define NTHR  512
#define LDK2  264    // 256 + 8 pad (ushorts): row stride 528 B

typedef __attribute__((ext_vector_type(4)))  float f32x4;
typedef __attribute__((ext_vector_type(16))) float f32x16;
typedef __attribute__((ext_vector_type(8)))  short bf16x8;

__device__ __forceinline__ ushort f2bf(float f) {
    union { __hip_bfloat16 b; ushort u; } v;
    v.b = __float2bfloat16(f);          // native cvt path (m240)
    return v.u;
}
__device__ __forceinline__ float bf2f(ushort h) {
    union { unsigned u; float f; } v; v.u = ((unsigned)h) << 16;
    return v.f;
}
__device__ __forceinline__ float sigmoid_f(float x) {
    return __builtin_amdgcn_rcpf(1.0f + __expf(-x));
}
__device__ __forceinline__ float tanh_f(float x) {
    float ax = fabsf(x);
    float e  = __expf(-2.0f * ax);
    float t  = (1.0f - e) * __builtin_amdgcn_rcpf(1.0f + e);
    return copysignf(t, x);
}

// --- weight prep: f32 [k][n] -> bf16 panels [n][k] in d_ws ---
// rows 0..255 = r cols (k<256: W_r, k>=256: U_r); 256..511 = z; 512..767 = h
__global__ void prep_w(const float* __restrict__ Wr, const float* __restrict__ Wz,
                       const float* __restrict__ Wh, const float* __restrict__ Ur,
                       const float* __restrict__ Uz, const float* __restrict__ Uh,
                       ushort* __restrict__ P)
{
    const int k  = blockIdx.x;          // 0..511
    const int kk = k & 255;
    const bool hi = k >= 256;
    for (int n = threadIdx.x; n < 768; n += 256) {
        float v;
        if (n < 256)      v = (hi ? Ur : Wr)[kk * 256 + n];
        else if (n < 512) v = (hi ? Uz : Wz)[kk * 256 + (n - 256)];
        else              v = (hi ? Uh : Wh)[kk * 256 + (n - 512)];
        P[(size_t)n * 512 + k] = f2bf(v);
    }
}

#define MFMA32(a, b, c) __builtin_amdgcn_mfma_f32_32x32x16_bf16((a), (b), (c), 0, 0, 0)

// B loads, phase 1 (r|z): b-step in [0,32): <16 -> W (ko=b*16), >=16 -> U (256+)
#define LBRZ(B, BR, BZ) do {                                                  \
    const int ko_ = ((B) < 16) ? (B) * 16 : 256 + ((B) - 16) * 16;            \
    BR = *(const bf16x8*)(pBr + ko_);                                         \
    BZ = *(const bf16x8*)(pBz + ko_);                                         \
} while (0)

// B loads, phase 2 (h): b-step <16 -> U_h (a-half, ko=256+), >=16 -> W_h (mgn)
#define LBH(B, BH) do {                                                       \
    const int ko_ = ((B) < 16) ? 256 + (B) * 16 : ((B) - 16) * 16;            \
    BH = *(const bf16x8*)(pBh + ko_);                                         \
} while (0)

// one 32x32x16 k16-step for r|z: 4 row-frags from SB at within-buffer step S16
#define STEP1(SB, S16, BR, BZ) do {                                           \
    const int kk_ = (S16) * 16;                                               \
    bf16x8 af_[4];                                                            \
    _Pragma("unroll") for (int rf_ = 0; rf_ < 4; ++rf_)                       \
        af_[rf_] = *(const bf16x8*)&SB[(rf_ * 32 + l31) * LDK2 + kk_ + hi8];  \
    _Pragma("unroll") for (int rf_ = 0; rf_ < 4; ++rf_) {                     \
        aR[rf_] = MFMA32(af_[rf_], BR, aR[rf_]);                              \
        aZ[rf_] = MFMA32(af_[rf_], BZ, aZ[rf_]);                              \
    }                                                                         \
} while (0)

#define STEP2(SB, S16, BH) do {                                               \
    const int kk_ = (S16) * 16;                                               \
    bf16x8 af_[4];                                                            \
    _Pragma("unroll") for (int rf_ = 0; rf_ < 4; ++rf_)                       \
        af_[rf_] = *(const bf16x8*)&SB[(rf_ * 32 + l31) * LDK2 + kk_ + hi8];  \
    _Pragma("unroll") for (int rf_ = 0; rf_ < 4; ++rf_)                       \
        aH[rf_] = MFMA32(af_[rf_], BH, aH[rf_]);                              \
} while (0)

// joint staging (current tile) into sbJ: 4-f32x4 chunks
#define LOADJ(C) do {                                                         \
    _Pragma("unroll") for (int i_ = 0; i_ < 4; ++i_) {                        \
        const int c_ = tid + ((C) * 4 + i_) * NTHR;                           \
        jv[i_] = *(const f32x4*)(joint + (r0 + (c_ >> 6)) * H + (c_ & 63) * 4); \
    }                                                                         \
} while (0)

#define COMMITJ(C) do {                                                       \
    _Pragma("unroll") for (int i_ = 0; i_ < 4; ++i_) {                        \
        const int c_ = tid + ((C) * 4 + i_) * NTHR;                           \
        ushort4 w_;                                                           \
        w_.x = f2bf(jv[i_][0]); w_.y = f2bf(jv[i_][1]);                       \
        w_.z = f2bf(jv[i_][2]); w_.w = f2bf(jv[i_][3]);                       \
        *(ushort4*)&sbJ[(c_ >> 6) * LDK2 + (c_ & 63) * 4] = w_;               \
    }                                                                         \
} while (0)

// NEXT-tile mgn staging into sbJ (free after phase-2 first half): 4-f32x4 chunks
#define LOADM2(C) do {                                                        \
    _Pragma("unroll") for (int i_ = 0; i_ < 4; ++i_) {                        \
        const int c_ = tid + ((C) * 4 + i_) * NTHR;                           \
        mv[i_] = *(const f32x4*)(mgn + (r0 + BM + (c_ >> 6)) * H + (c_ & 63) * 4); \
    }                                                                         \
} while (0)

#define COMMITM2(C) do {                                                      \
    _Pragma("unroll") for (int i_ = 0; i_ < 4; ++i_) {                        \
        const int c_ = tid + ((C) * 4 + i_) * NTHR;                           \
        ushort4 w_;                                                           \
        w_.x = f2bf(mv[i_][0]); w_.y = f2bf(mv[i_][1]);                       \
        w_.z = f2bf(mv[i_][2]); w_.w = f2bf(mv[i_][3]);                       \
        *(ushort4*)&sbJ[(c_ >> 6) * LDK2 + (c_ & 63) * 4] = w_;               \
    }                                                                         \
} while (0)

__global__ __launch_bounds__(NTHR, 2)
void gru_main(const float* __restrict__ joint, const float* __restrict__ mgn,
              const ushort* __restrict__ P,
              const float* __restrict__ br_, const float* __restrict__ bz_,
              const float* __restrict__ bh_, float* __restrict__ out)
{
    __shared__ ushort sbA[BM * LDK2];
    __shared__ ushort sbB[BM * LDK2];

    const int tid  = threadIdx.x;
    const int wave = tid >> 6;          // 0..7
    const int lane = tid & 63;
    const int l31  = lane & 31;
    const int hi8  = (lane >> 5) * 8;   // A/B frag k-offset
    const int hi4  = (lane >> 5) * 4;   // C/D row offset
    const int colbase = wave * 32;      // 8 waves x 32 cols: B read once per tile
    const int col  = colbase + l31;

    const ushort* __restrict__ pBr = P + (size_t)col * 512 + hi8;
    const ushort* __restrict__ pBz = pBr + (size_t)256 * 512;
    const ushort* __restrict__ pBh = pBr + (size_t)512 * 512;

    const float brv = br_[col];
    const float bzv = bz_[col];
    const float bhv = bh_[col];

    // --- upfront: stage mgn(tile 0) -> sbA ---
    {
        const size_t rr = (size_t)blockIdx.x * (2 * BM);
        #pragma unroll
        for (int b = 0; b < 2; ++b) {
            f32x4 v[8];
            #pragma unroll
            for (int i = 0; i < 8; ++i) {
                const int c = tid + (b * 8 + i) * NTHR;
                v[i] = *(const f32x4*)(mgn + (rr + (c >> 6)) * H + (c & 63) * 4);
            }
            #pragma unroll
            for (int i = 0; i < 8; ++i) {
                const int c = tid + (b * 8 + i) * NTHR;
                ushort4 w;
                w.x = f2bf(v[i][0]); w.y = f2bf(v[i][1]);
                w.z = f2bf(v[i][2]); w.w = f2bf(v[i][3]);
                *(ushort4*)&sbA[(c >> 6) * LDK2 + (c & 63) * 4] = w;
            }
        }
    }
    __syncthreads();

    ushort* sbM = sbA;   // mgn buffer for current tile
    ushort* sbJ = sbB;   // joint -> a buffer for current tile

    #pragma unroll
    for (int t = 0; t < 2; ++t) {
        const size_t r0 = (size_t)blockIdx.x * (2 * BM) + (size_t)t * BM;

        f32x16 aR[4], aZ[4];
        #pragma unroll
        for (int rf = 0; rf < 4; ++rf)
            #pragma unroll
            for (int e = 0; e < 16; ++e) { aR[rf][e] = 0.f; aZ[rf][e] = 0.f; }

        // --- phase 1 first half: 16 steps on sbM (W); joint(t) -> sbJ pipelined ---
        {
            f32x4 jv[4];
            bf16x8 bR[4], bZ[4];
            #pragma unroll
            for (int s = 0; s < 4; ++s) LBRZ(s, bR[s], bZ[s]);
            LOADJ(0);
            #pragma unroll
            for (int s = 0; s < 16; ++s) {
                STEP1(sbM, s, bR[s & 3], bZ[s & 3]);
                LBRZ(s + 4, bR[s & 3], bZ[s & 3]);
                if (s == 2)       { COMMITJ(0); LOADJ(1); }
                else if (s == 5)  { COMMITJ(1); LOADJ(2); }
                else if (s == 8)  { COMMITJ(2); LOADJ(3); }
                else if (s == 11) { COMMITJ(3); }
            }
            __syncthreads();                    // sbJ (joint) complete
            // --- phase 1 second half: 16 steps on sbJ (U) ---
            #pragma unroll
            for (int s = 0; s < 16; ++s) {
                STEP1(sbJ, s, bR[s & 3], bZ[s & 3]);
                if (s < 12) LBRZ(s + 20, bR[s & 3], bZ[s & 3]);
            }
        }
        __syncthreads();                        // all waves done reading joint

        // hoist first 4 phase-2 B loads (a-half, independent of gates)
        bf16x8 bH[4];
        #pragma unroll
        for (int s = 0; s < 4; ++s) LBH(s, bH[s]);

        // --- gates: r -> a (overwrite sbJ); z,h packed to regs as bf16 ---
        uint hs[32], zs[32];
        #pragma unroll
        for (int rf = 0; rf < 4; ++rf)
            #pragma unroll
            for (int m = 0; m < 16; m += 2) {
                ushort hb[2], zb[2];
                #pragma unroll
                for (int e = 0; e < 2; ++e) {
                    const int mm  = m + e;
                    const int row = rf * 32 + (mm & 3) + 8 * (mm >> 2) + hi4;
                    const int idx = row * LDK2 + col;
                    const float r = sigmoid_f(aR[rf][mm] + brv);
                    hb[e] = sbJ[idx];
                    sbJ[idx] = f2bf(bf2f(hb[e]) * r);
                    zb[e] = f2bf(sigmoid_f(aZ[rf][mm] + bzv));
                }
                hs[rf * 8 + (m >> 1)] = (uint)hb[0] | ((uint)hb[1] << 16);
                zs[rf * 8 + (m >> 1)] = (uint)zb[0] | ((uint)zb[1] << 16);
            }
        __syncthreads();                        // a visible

        // --- phase 2 first half: 16 steps on sbJ (a @ U_h) ---
        f32x16 aH[4];
        #pragma unroll
        for (int rf = 0; rf < 4; ++rf)
            #pragma unroll
            for (int e = 0; e < 16; ++e) aH[rf][e] = 0.f;

        #pragma unroll
        for (int s = 0; s < 16; ++s) {
            STEP2(sbJ, s, bH[s & 3]);
            LBH(s + 4, bH[s & 3]);
        }
        __syncthreads();                        // sbJ free: stage next-tile mgn into it

        // --- phase 2 second half: 16 steps on sbM (mgn @ W_h);
        //     next-tile mgn -> sbJ staged under the MFMA stream (t==0 only) ---
        {
            f32x4 mv[4];
            #pragma unroll
            for (int s = 0; s < 16; ++s) {
                STEP2(sbM, s, bH[s & 3]);
                if (s < 12) LBH(s + 20, bH[s & 3]);
                if (t == 0) {
                    if (s == 0)       { LOADM2(0); }
                    else if (s == 2)  { COMMITM2(0); LOADM2(1); }
                    else if (s == 5)  { COMMITM2(1); LOADM2(2); }
                    else if (s == 8)  { COMMITM2(2); LOADM2(3); }
                    else if (s == 11) { COMMITM2(3); }
                }
            }
        }

        // --- epilogue: out = ht + z*(h - ht); h,z from packed regs ---
        #pragma unroll
        for (int rf = 0; rf < 4; ++rf)
            #pragma unroll
            for (int m = 0; m < 16; ++m) {
                const int row = rf * 32 + (m & 3) + 8 * (m >> 2) + hi4;
                const float ht = tanh_f(aH[rf][m] + bhv);
                const uint pk  = hs[rf * 8 + (m >> 1)];
                const uint pz  = zs[rf * 8 + (m >> 1)];
                const float h  = bf2f((ushort)(pk >> ((m & 1) * 16)));
                const float z  = bf2f((ushort)(pz >> ((m & 1) * 16)));
                out[(r0 + row) * H + col] = ht + z * (h - ht);
            }

        __syncthreads();    // sbM reads done; next-tile mgn commits visible
        ushort* tmp = sbM; sbM = sbJ; sbJ = tmp;   // ping-pong roles
    }
}

extern "C" void kernel_launch(void* const* d_in, const int* in_sizes, int n_in,
                              void* d_out, int out_size, void* d_ws, size_t ws_size,
                              hipStream_t stream)
{
    const float* joint = (const float*)d_in[0];
    const float* mgn   = (const float*)d_in[1];
    const float* Wr    = (const float*)d_in[2];
    const float* Wz    = (const float*)d_in[3];
    const float* Wh    = (const float*)d_in[4];
    const float* Ur    = (const float*)d_in[5];
    const float* Uz    = (const float*)d_in[6];
    const float* Uh    = (const float*)d_in[7];
    const float* br    = (const float*)d_in[8];
    const float* bz    = (const float*)d_in[9];
    const float* bh    = (const float*)d_in[10];

    ushort* P  = (ushort*)d_ws;          // 786 KB scratch
    float* out = (float*)d_out;

    prep_w<<<512, 256, 0, stream>>>(Wr, Wz, Wh, Ur, Uz, Uh, P);

    const int nrows = 65536;
    gru_main<<<nrows / (2 * BM), NTHR, 0, stream>>>(joint, mgn, P, br, bz, bh, out);
}

// Round 17
// 134.755 us; speedup vs baseline: 1.1991x; 1.1991x over previous
//
#include <hip/hip_runtime.h>
#include <hip/hip_bf16.h>

#define H     256
#define BM    128
#define NTHR  512
#define LDK2  264    // 256 + 8 pad (ushorts): row stride 528 B

typedef __attribute__((ext_vector_type(4)))  float f32x4;
typedef __attribute__((ext_vector_type(16))) float f32x16;
typedef __attribute__((ext_vector_type(8)))  short bf16x8;

__device__ __forceinline__ ushort f2bf(float f) {
    union { __hip_bfloat16 b; ushort u; } v;
    v.b = __float2bfloat16(f);          // native cvt path
    return v.u;
}
__device__ __forceinline__ float bf2f(ushort h) {
    union { unsigned u; float f; } v; v.u = ((unsigned)h) << 16;
    return v.f;
}
__device__ __forceinline__ float sigmoid_f(float x) {
    return __builtin_amdgcn_rcpf(1.0f + __expf(-x));
}
__device__ __forceinline__ float tanh_f(float x) {
    float ax = fabsf(x);
    float e  = __expf(-2.0f * ax);
    float t  = (1.0f - e) * __builtin_amdgcn_rcpf(1.0f + e);
    return copysignf(t, x);
}

// --- weight prep: f32 [k][n] -> bf16 panels [n][k] in d_ws ---
// rows 0..255 = r cols (k<256: W_r, k>=256: U_r); 256..511 = z; 512..767 = h
__global__ void prep_w(const float* __restrict__ Wr, const float* __restrict__ Wz,
                       const float* __restrict__ Wh, const float* __restrict__ Ur,
                       const float* __restrict__ Uz, const float* __restrict__ Uh,
                       ushort* __restrict__ P)
{
    const int k  = blockIdx.x;          // 0..511
    const int kk = k & 255;
    const bool hi = k >= 256;
    for (int n = threadIdx.x; n < 768; n += 256) {
        float v;
        if (n < 256)      v = (hi ? Ur : Wr)[kk * 256 + n];
        else if (n < 512) v = (hi ? Uz : Wz)[kk * 256 + (n - 256)];
        else              v = (hi ? Uh : Wh)[kk * 256 + (n - 512)];
        P[(size_t)n * 512 + k] = f2bf(v);
    }
}

#define MFMA32(a, b, c) __builtin_amdgcn_mfma_f32_32x32x16_bf16((a), (b), (c), 0, 0, 0)

// B loads, phase 1 (r|z): b-step in [0,32): <16 -> W (ko=b*16), >=16 -> U (256+)
// two col-frags per gate (cf stride = 32 cols = 32*512 elements)
#define LBRZ(B, R0, R1, Z0, Z1) do {                                          \
    const int ko_ = ((B) < 16) ? (B) * 16 : 256 + ((B) - 16) * 16;            \
    R0 = *(const bf16x8*)(pBr + ko_);                                         \
    R1 = *(const bf16x8*)(pBr + (size_t)32 * 512 + ko_);                      \
    Z0 = *(const bf16x8*)(pBz + ko_);                                         \
    Z1 = *(const bf16x8*)(pBz + (size_t)32 * 512 + ko_);                      \
} while (0)

// B loads, phase 2 (h): b-step <16 -> U_h (a-half, ko=256+), >=16 -> W_h (mgn)
#define LBH(B, H0, H1) do {                                                   \
    const int ko_ = ((B) < 16) ? 256 + (B) * 16 : ((B) - 16) * 16;            \
    H0 = *(const bf16x8*)(pBh + ko_);                                         \
    H1 = *(const bf16x8*)(pBh + (size_t)32 * 512 + ko_);                      \
} while (0)

// one 32x32x16 k16-step for r|z: 2 row-frags, 2 col-frags -> 8 MFMA, 2 ds_reads
#define STEP1(SB, S16, R0, R1, Z0, Z1) do {                                   \
    const int kk_ = (S16) * 16;                                               \
    bf16x8 a0_ = *(const bf16x8*)&SB[(rowbase + l31) * LDK2 + kk_ + hi8];     \
    bf16x8 a1_ = *(const bf16x8*)&SB[(rowbase + 32 + l31) * LDK2 + kk_ + hi8];\
    aR[0][0] = MFMA32(a0_, R0, aR[0][0]);                                     \
    aR[1][0] = MFMA32(a1_, R0, aR[1][0]);                                     \
    aZ[0][0] = MFMA32(a0_, Z0, aZ[0][0]);                                     \
    aZ[1][0] = MFMA32(a1_, Z0, aZ[1][0]);                                     \
    aR[0][1] = MFMA32(a0_, R1, aR[0][1]);                                     \
    aR[1][1] = MFMA32(a1_, R1, aR[1][1]);                                     \
    aZ[0][1] = MFMA32(a0_, Z1, aZ[0][1]);                                     \
    aZ[1][1] = MFMA32(a1_, Z1, aZ[1][1]);                                     \
} while (0)

#define STEP2(SB, S16, H0, H1) do {                                           \
    const int kk_ = (S16) * 16;                                               \
    bf16x8 a0_ = *(const bf16x8*)&SB[(rowbase + l31) * LDK2 + kk_ + hi8];     \
    bf16x8 a1_ = *(const bf16x8*)&SB[(rowbase + 32 + l31) * LDK2 + kk_ + hi8];\
    aH[0][0] = MFMA32(a0_, H0, aH[0][0]);                                     \
    aH[1][0] = MFMA32(a1_, H0, aH[1][0]);                                     \
    aH[0][1] = MFMA32(a0_, H1, aH[0][1]);                                     \
    aH[1][1] = MFMA32(a1_, H1, aH[1][1]);                                     \
} while (0)

// joint staging: 4-f32x4 chunks (16 regs), issue early / commit ~3 steps later
#define LOADJ(C) do {                                                         \
    _Pragma("unroll") for (int i_ = 0; i_ < 4; ++i_) {                        \
        const int c_ = tid + ((C) * 4 + i_) * NTHR;                           \
        jv[i_] = *(const f32x4*)(joint + (r0 + (c_ >> 6)) * H + (c_ & 63) * 4); \
    }                                                                         \
} while (0)

#define COMMITJ(C) do {                                                       \
    _Pragma("unroll") for (int i_ = 0; i_ < 4; ++i_) {                        \
        const int c_ = tid + ((C) * 4 + i_) * NTHR;                           \
        ushort4 w_;                                                           \
        w_.x = f2bf(jv[i_][0]); w_.y = f2bf(jv[i_][1]);                       \
        w_.z = f2bf(jv[i_][2]); w_.w = f2bf(jv[i_][3]);                       \
        *(ushort4*)&sb1[(c_ >> 6) * LDK2 + (c_ & 63) * 4] = w_;               \
    }                                                                         \
} while (0)

__global__ __launch_bounds__(NTHR, 2)
void gru_main(const float* __restrict__ joint, const float* __restrict__ mgn,
              const ushort* __restrict__ P,
              const float* __restrict__ br_, const float* __restrict__ bz_,
              const float* __restrict__ bh_, float* __restrict__ out)
{
    __shared__ ushort sb0[BM * LDK2];   // mgn bf16
    __shared__ ushort sb1[BM * LDK2];   // joint bf16 -> a = joint*r

    const int tid  = threadIdx.x;
    const int wave = tid >> 6;          // 0..7
    const int lane = tid & 63;
    const int l31  = lane & 31;
    const int hi8  = (lane >> 5) * 8;   // A/B frag k-offset
    const int hi4  = (lane >> 5) * 4;   // C/D row offset
    const int rowbase = (wave >> 2) * 64;   // 2 row-groups of 64
    const int colb    = (wave & 3) * 64;    // 4 col-groups of 64
    const size_t r0 = (size_t)blockIdx.x * BM;

    const ushort* __restrict__ pBr = P + (size_t)(colb + l31) * 512 + hi8;
    const ushort* __restrict__ pBz = pBr + (size_t)256 * 512;
    const ushort* __restrict__ pBh = pBr + (size_t)512 * 512;

    // --- stage mgn -> sb0 fully upfront (2 batches of 8 f32x4) ---
    #pragma unroll
    for (int b = 0; b < 2; ++b) {
        f32x4 mv[8];
        #pragma unroll
        for (int i = 0; i < 8; ++i) {
            const int c = tid + (b * 8 + i) * NTHR;
            mv[i] = *(const f32x4*)(mgn + (r0 + (c >> 6)) * H + (c & 63) * 4);
        }
        #pragma unroll
        for (int i = 0; i < 8; ++i) {
            const int c = tid + (b * 8 + i) * NTHR;
            ushort4 w;
            w.x = f2bf(mv[i][0]); w.y = f2bf(mv[i][1]);
            w.z = f2bf(mv[i][2]); w.w = f2bf(mv[i][3]);
            *(ushort4*)&sb0[(c >> 6) * LDK2 + (c & 63) * 4] = w;
        }
    }
    __syncthreads();

    f32x16 aR[2][2], aZ[2][2];
    #pragma unroll
    for (int rf = 0; rf < 2; ++rf)
        #pragma unroll
        for (int cf = 0; cf < 2; ++cf)
            #pragma unroll
            for (int e = 0; e < 16; ++e) { aR[rf][cf][e] = 0.f; aZ[rf][cf][e] = 0.f; }

    // --- phase 1: 32 k16-steps (mgn: sb0, joint: sb1), depth-2 B roll,
    //     joint staged in 4x4 chunks under the first 16 steps ---
    {
        f32x4 jv[4];
        bf16x8 rA0, rA1, zA0, zA1, rB0, rB1, zB0, zB1;
        LBRZ(0, rA0, rA1, zA0, zA1);
        LBRZ(1, rB0, rB1, zB0, zB1);
        LOADJ(0);
        STEP1(sb0, 0, rA0, rA1, zA0, zA1);  LBRZ(2, rA0, rA1, zA0, zA1);
        STEP1(sb0, 1, rB0, rB1, zB0, zB1);  LBRZ(3, rB0, rB1, zB0, zB1);
        STEP1(sb0, 2, rA0, rA1, zA0, zA1);  LBRZ(4, rA0, rA1, zA0, zA1);
        COMMITJ(0); LOADJ(1);
        STEP1(sb0, 3, rB0, rB1, zB0, zB1);  LBRZ(5, rB0, rB1, zB0, zB1);
        STEP1(sb0, 4, rA0, rA1, zA0, zA1);  LBRZ(6, rA0, rA1, zA0, zA1);
        STEP1(sb0, 5, rB0, rB1, zB0, zB1);  LBRZ(7, rB0, rB1, zB0, zB1);
        COMMITJ(1); LOADJ(2);
        STEP1(sb0, 6, rA0, rA1, zA0, zA1);  LBRZ(8, rA0, rA1, zA0, zA1);
        STEP1(sb0, 7, rB0, rB1, zB0, zB1);  LBRZ(9, rB0, rB1, zB0, zB1);
        STEP1(sb0, 8, rA0, rA1, zA0, zA1);  LBRZ(10, rA0, rA1, zA0, zA1);
        COMMITJ(2); LOADJ(3);
        STEP1(sb0, 9, rB0, rB1, zB0, zB1);  LBRZ(11, rB0, rB1, zB0, zB1);
        STEP1(sb0, 10, rA0, rA1, zA0, zA1); LBRZ(12, rA0, rA1, zA0, zA1);
        STEP1(sb0, 11, rB0, rB1, zB0, zB1); LBRZ(13, rB0, rB1, zB0, zB1);
        COMMITJ(3);
        STEP1(sb0, 12, rA0, rA1, zA0, zA1); LBRZ(14, rA0, rA1, zA0, zA1);
        STEP1(sb0, 13, rB0, rB1, zB0, zB1); LBRZ(15, rB0, rB1, zB0, zB1);
        STEP1(sb0, 14, rA0, rA1, zA0, zA1); LBRZ(16, rA0, rA1, zA0, zA1);
        STEP1(sb0, 15, rB0, rB1, zB0, zB1); LBRZ(17, rB0, rB1, zB0, zB1);
        __syncthreads();                        // sb1 (joint) complete
        STEP1(sb1, 0, rA0, rA1, zA0, zA1);  LBRZ(18, rA0, rA1, zA0, zA1);
        STEP1(sb1, 1, rB0, rB1, zB0, zB1);  LBRZ(19, rB0, rB1, zB0, zB1);
        STEP1(sb1, 2, rA0, rA1, zA0, zA1);  LBRZ(20, rA0, rA1, zA0, zA1);
        STEP1(sb1, 3, rB0, rB1, zB0, zB1);  LBRZ(21, rB0, rB1, zB0, zB1);
        STEP1(sb1, 4, rA0, rA1, zA0, zA1);  LBRZ(22, rA0, rA1, zA0, zA1);
        STEP1(sb1, 5, rB0, rB1, zB0, zB1);  LBRZ(23, rB0, rB1, zB0, zB1);
        STEP1(sb1, 6, rA0, rA1, zA0, zA1);  LBRZ(24, rA0, rA1, zA0, zA1);
        STEP1(sb1, 7, rB0, rB1, zB0, zB1);  LBRZ(25, rB0, rB1, zB0, zB1);
        STEP1(sb1, 8, rA0, rA1, zA0, zA1);  LBRZ(26, rA0, rA1, zA0, zA1);
        STEP1(sb1, 9, rB0, rB1, zB0, zB1);  LBRZ(27, rB0, rB1, zB0, zB1);
        STEP1(sb1, 10, rA0, rA1, zA0, zA1); LBRZ(28, rA0, rA1, zA0, zA1);
        STEP1(sb1, 11, rB0, rB1, zB0, zB1); LBRZ(29, rB0, rB1, zB0, zB1);
        STEP1(sb1, 12, rA0, rA1, zA0, zA1); LBRZ(30, rA0, rA1, zA0, zA1);
        STEP1(sb1, 13, rB0, rB1, zB0, zB1); LBRZ(31, rB0, rB1, zB0, zB1);
        STEP1(sb1, 14, rA0, rA1, zA0, zA1);
        STEP1(sb1, 15, rB0, rB1, zB0, zB1);
    }
    __syncthreads();   // all waves done reading joint in sb1

    // --- hoist first 4 phase-2 B loads (a-half, independent of gates) ---
    bf16x8 hA0, hA1, hB0, hB1, hC0, hC1, hD0, hD1;
    LBH(0, hA0, hA1); LBH(1, hB0, hB1); LBH(2, hC0, hC1); LBH(3, hD0, hD1);

    // --- gates: r -> a (overwrite sb1); z,h packed to regs as bf16 ---
    uint hs[32], zs[32];
    {
        #pragma unroll
        for (int rf = 0; rf < 2; ++rf)
            #pragma unroll
            for (int cf = 0; cf < 2; ++cf) {
                const int c   = colb + cf * 32 + l31;
                const float brv = br_[c];
                const float bzv = bz_[c];
                #pragma unroll
                for (int m = 0; m < 16; m += 2) {
                    ushort hb[2], zb[2];
                    #pragma unroll
                    for (int e = 0; e < 2; ++e) {
                        const int mm  = m + e;
                        const int row = rowbase + rf * 32 + (mm & 3) + 8 * (mm >> 2) + hi4;
                        const int idx = row * LDK2 + c;
                        const float r = sigmoid_f(aR[rf][cf][mm] + brv);
                        hb[e] = sb1[idx];
                        sb1[idx] = f2bf(bf2f(hb[e]) * r);
                        zb[e] = f2bf(sigmoid_f(aZ[rf][cf][mm] + bzv));
                    }
                    hs[(rf * 2 + cf) * 8 + (m >> 1)] = (uint)hb[0] | ((uint)hb[1] << 16);
                    zs[(rf * 2 + cf) * 8 + (m >> 1)] = (uint)zb[0] | ((uint)zb[1] << 16);
                }
            }
    }
    __syncthreads();

    // --- phase 2: 32 k16-steps (a @ U_h: sb1, then mgn @ W_h: sb0), depth-4 roll ---
    f32x16 aH[2][2];
    #pragma unroll
    for (int rf = 0; rf < 2; ++rf)
        #pragma unroll
        for (int cf = 0; cf < 2; ++cf)
            #pragma unroll
            for (int e = 0; e < 16; ++e) aH[rf][cf][e] = 0.f;

    {
        STEP2(sb1, 0, hA0, hA1);  LBH(4, hA0, hA1);
        STEP2(sb1, 1, hB0, hB1);  LBH(5, hB0, hB1);
        STEP2(sb1, 2, hC0, hC1);  LBH(6, hC0, hC1);
        STEP2(sb1, 3, hD0, hD1);  LBH(7, hD0, hD1);
        STEP2(sb1, 4, hA0, hA1);  LBH(8, hA0, hA1);
        STEP2(sb1, 5, hB0, hB1);  LBH(9, hB0, hB1);
        STEP2(sb1, 6, hC0, hC1);  LBH(10, hC0, hC1);
        STEP2(sb1, 7, hD0, hD1);  LBH(11, hD0, hD1);
        STEP2(sb1, 8, hA0, hA1);  LBH(12, hA0, hA1);
        STEP2(sb1, 9, hB0, hB1);  LBH(13, hB0, hB1);
        STEP2(sb1, 10, hC0, hC1); LBH(14, hC0, hC1);
        STEP2(sb1, 11, hD0, hD1); LBH(15, hD0, hD1);
        STEP2(sb1, 12, hA0, hA1); LBH(16, hA0, hA1);
        STEP2(sb1, 13, hB0, hB1); LBH(17, hB0, hB1);
        STEP2(sb1, 14, hC0, hC1); LBH(18, hC0, hC1);
        STEP2(sb1, 15, hD0, hD1); LBH(19, hD0, hD1);
        STEP2(sb0, 0, hA0, hA1);  LBH(20, hA0, hA1);
        STEP2(sb0, 1, hB0, hB1);  LBH(21, hB0, hB1);
        STEP2(sb0, 2, hC0, hC1);  LBH(22, hC0, hC1);
        STEP2(sb0, 3, hD0, hD1);  LBH(23, hD0, hD1);
        STEP2(sb0, 4, hA0, hA1);  LBH(24, hA0, hA1);
        STEP2(sb0, 5, hB0, hB1);  LBH(25, hB0, hB1);
        STEP2(sb0, 6, hC0, hC1);  LBH(26, hC0, hC1);
        STEP2(sb0, 7, hD0, hD1);  LBH(27, hD0, hD1);
        STEP2(sb0, 8, hA0, hA1);  LBH(28, hA0, hA1);
        STEP2(sb0, 9, hB0, hB1);  LBH(29, hB0, hB1);
        STEP2(sb0, 10, hC0, hC1); LBH(30, hC0, hC1);
        STEP2(sb0, 11, hD0, hD1); LBH(31, hD0, hD1);
        STEP2(sb0, 12, hA0, hA1);
        STEP2(sb0, 13, hB0, hB1);
        STEP2(sb0, 14, hC0, hC1);
        STEP2(sb0, 15, hD0, hD1);
    }

    // --- epilogue: out = ht + z*(h - ht); h,z from packed regs ---
    {
        #pragma unroll
        for (int rf = 0; rf < 2; ++rf)
            #pragma unroll
            for (int cf = 0; cf < 2; ++cf) {
                const int c = colb + cf * 32 + l31;
                const float bhv = bh_[c];
                #pragma unroll
                for (int m = 0; m < 16; ++m) {
                    const int row = rowbase + rf * 32 + (m & 3) + 8 * (m >> 2) + hi4;
                    const float ht = tanh_f(aH[rf][cf][m] + bhv);
                    const uint pk  = hs[(rf * 2 + cf) * 8 + (m >> 1)];
                    const uint pz  = zs[(rf * 2 + cf) * 8 + (m >> 1)];
                    const float h  = bf2f((ushort)(pk >> ((m & 1) * 16)));
                    const float z  = bf2f((ushort)(pz >> ((m & 1) * 16)));
                    out[(r0 + row) * H + c] = ht + z * (h - ht);
                }
            }
    }
}

extern "C" void kernel_launch(void* const* d_in, const int* in_sizes, int n_in,
                              void* d_out, int out_size, void* d_ws, size_t ws_size,
                              hipStream_t stream)
{
    const float* joint = (const float*)d_in[0];
    const float* mgn   = (const float*)d_in[1];
    const float* Wr    = (const float*)d_in[2];
    const float* Wz    = (const float*)d_in[3];
    const float* Wh    = (const float*)d_in[4];
    const float* Ur    = (const float*)d_in[5];
    const float* Uz    = (const float*)d_in[6];
    const float* Uh    = (const float*)d_in[7];
    const float* br    = (const float*)d_in[8];
    const float* bz    = (const float*)d_in[9];
    const float* bh    = (const float*)d_in[10];

    ushort* P  = (ushort*)d_ws;          // 786 KB scratch
    float* out = (float*)d_out;

    prep_w<<<512, 256, 0, stream>>>(Wr, Wz, Wh, Ur, Uz, Uh, P);

    const int nrows = 65536;
    gru_main<<<nrows / BM, NTHR, 0, stream>>>(joint, mgn, P, br, bz, bh, out);
}